// Round 1
// 2660.467 us; speedup vs baseline: 1.1268x; 1.1268x over previous
//
#include <hip/hip_runtime.h>
#include <hip/hip_bf16.h>
#include <cstdint>
#include <cstddef>

#define NN 20000
#define NE 200000
#define NG 128
#define HID 256

typedef __bf16 bfrag8 __attribute__((ext_vector_type(8)));  // 8 bf16 (4 VGPRs)
typedef float  accf4  __attribute__((ext_vector_type(4)));  // 4 fp32 acc

__device__ __forceinline__ unsigned short f2bf(float f) {
    union { float f; unsigned int i; } x; x.f = f;
    unsigned int r = x.i + 0x7fffu + ((x.i >> 16) & 1u);  // RNE
    return (unsigned short)(r >> 16);
}
__device__ __forceinline__ __bf16 f2bf16t(float f) {
    union { unsigned short u; __bf16 b; } x; x.u = f2bf(f); return x.b;
}
__device__ __forceinline__ float sspf(float x) {
    // softplus(x) - log(2), numerically stable
    return fmaxf(x, 0.f) + log1pf(expf(-fabsf(x))) - 0.69314718055994530942f;
}

// async 16B global -> LDS (per-lane global addr, lane-linear LDS dest: base + lane*16)
__device__ __forceinline__ void gload_lds16(const void* g, void* l) {
    __builtin_amdgcn_global_load_lds(
        (const __attribute__((address_space(1))) unsigned int*)g,
        (__attribute__((address_space(3))) unsigned int*)l,
        16, 0, 0);
}

// A-operand spec: virtual A[M, nblocks*256] = concat of up to 4 [.,256] sources,
// each with optional row-index indirection (nullptr => identity) and a per-block
// dtype flag (f32mask bit b set => base[b] is const float*, else bf16).
struct ASpec {
    const void* base[4];
    const int* idx[4];
    int f32mask;
    int nblocks;
};

// out[M,256] = ssp( A_virtual[M,K] @ Wbf16[256,K]^T ) (+ resid_f32), out f32 or bf16.
//
// m97-style LDS-staged MFMA GEMM:
//   block = 64 rows x 256 cols, 4 waves; wave w owns rows 0..63 x cols [w*64, w*64+64)
//   as a 4x4 grid of 16x16 fragments. K-step = 32.
//   LDS per K-step: A tile 64x32 (4 subtiles of 1KB) + W tile 256x32 (16 subtiles),
//   double-buffered = 40KB. Layout is fragment-ordered: subtile_base + lane*16 holds
//   (row = lane&15, k = (lane>>4)*8 .. +8) -> linear, conflict-free ds_read_b128, and
//   matches global_load_lds's lane-linear destination.
//   Wave w stages A-subtile t=w (its 16 rows, per-lane gather addresses) and
//   W-subtiles ct = w*4..w*4+3. f32 A-sources go through VGPR convert + ds_write_b128.
//
// In-place safe when out aliases an identity-indexed A block: each block reads only its
// own 64 rows; all global A reads are vmcnt-drained at the final __syncthreads before
// the epilogue stores; clamped tail rows never store (r < M guard).
__global__ __launch_bounds__(256) void gemm_ssp_kernel(
    ASpec A, const unsigned short* __restrict__ W,
    void* __restrict__ out, int out_f32,
    const float* __restrict__ resid, int M)
{
    __shared__ unsigned short lds[2][10240];   // 2 x 20KB: [A: 4*512 | B: 16*512] shorts

    const int K    = A.nblocks * HID;
    const int lane = threadIdx.x & 63;
    const int wave = threadIdx.x >> 6;
    const int l15  = lane & 15;
    const int kg   = lane >> 4;
    const int rowbase = blockIdx.x * 64;

    // ---- staging setup: per-thread fixed source pointers ----
    // A: this thread stages row (rowbase + wave*16 + l15), 16B chunk kg.
    const int arow = rowbase + wave * 16 + l15;
    const int arc  = arow < M ? arow : (M - 1);
    auto mkap = [&](int b) -> const char* {
        if (b >= A.nblocks) return (const char*)A.base[0];
        const int rid = A.idx[b] ? A.idx[b][arc] : arc;
        const int e4  = (A.f32mask >> b) & 1;
        return (const char*)A.base[b] + (size_t)rid * (size_t)(HID * (e4 ? 4 : 2));
    };
    const char* ap0 = mkap(0);
    const char* ap1 = mkap(1);
    const char* ap2 = mkap(2);
    const char* ap3 = mkap(3);

    // B: this thread stages W rows (wave*4+j)*16 + l15, k-chunk kg, j=0..3.
    const unsigned short* wp0 = W + (size_t)((wave * 4 + 0) * 16 + l15) * K + kg * 8;
    const unsigned short* wp1 = W + (size_t)((wave * 4 + 1) * 16 + l15) * K + kg * 8;
    const unsigned short* wp2 = W + (size_t)((wave * 4 + 2) * 16 + l15) * K + kg * 8;
    const unsigned short* wp3 = W + (size_t)((wave * 4 + 3) * 16 + l15) * K + kg * 8;

    auto STAGE = [&](int buf, int kt) {
        unsigned short* ldsb = &lds[buf][0];
        const int b   = kt >> 3;                    // which 256-col source block
        const int kin = (kt & 7) * 32 + kg * 8;     // element offset within source row
        const char* ap = (b == 0) ? ap0 : (b == 1) ? ap1 : (b == 2) ? ap2 : ap3;
        if ((A.f32mask >> b) & 1) {
            const float* p = (const float*)ap + kin;
            const float4 x = ((const float4*)p)[0];
            const float4 y = ((const float4*)p)[1];
            bfrag8 f;
            f[0] = f2bf16t(x.x); f[1] = f2bf16t(x.y);
            f[2] = f2bf16t(x.z); f[3] = f2bf16t(x.w);
            f[4] = f2bf16t(y.x); f[5] = f2bf16t(y.y);
            f[6] = f2bf16t(y.z); f[7] = f2bf16t(y.w);
            *(bfrag8*)((char*)ldsb + wave * 1024 + lane * 16) = f;
        } else {
            gload_lds16((const unsigned short*)ap + kin, ldsb + wave * 512);
        }
        const int koff = kt * 32;
        gload_lds16(wp0 + koff, ldsb + 2048 + (wave * 4 + 0) * 512);
        gload_lds16(wp1 + koff, ldsb + 2048 + (wave * 4 + 1) * 512);
        gload_lds16(wp2 + koff, ldsb + 2048 + (wave * 4 + 2) * 512);
        gload_lds16(wp3 + koff, ldsb + 2048 + (wave * 4 + 3) * 512);
    };

    accf4 acc[4][4];
    #pragma unroll
    for (int m = 0; m < 4; m++)
        #pragma unroll
        for (int n = 0; n < 4; n++)
            acc[m][n] = (accf4){0.f, 0.f, 0.f, 0.f};

    const int ksteps = A.nblocks * 8;

    STAGE(0, 0);
    __syncthreads();                                // drains vmcnt+lgkm: buf0 ready

    for (int kt = 0; kt < ksteps; ++kt) {
        const int cur = kt & 1;
        if (kt + 1 < ksteps) STAGE(cur ^ 1, kt + 1);

        const unsigned short* ldsb = &lds[cur][0];
        bfrag8 af[4], bf[4];
        #pragma unroll
        for (int m = 0; m < 4; m++)
            af[m] = *(const bfrag8*)((const char*)ldsb + m * 1024 + lane * 16);
        #pragma unroll
        for (int n = 0; n < 4; n++)
            bf[n] = *(const bfrag8*)((const char*)ldsb + 4096 + (wave * 4 + n) * 1024 + lane * 16);
        #pragma unroll
        for (int m = 0; m < 4; m++)
            #pragma unroll
            for (int n = 0; n < 4; n++)
                acc[m][n] = __builtin_amdgcn_mfma_f32_16x16x32_bf16(af[m], bf[n], acc[m][n], 0, 0, 0);

        __syncthreads();   // readers done with buf[cur] + next buf's loads drained
    }

    // epilogue: D fragment (col = l15, row = kg*4 + rg), cols = wave*64 + n*16 + l15
    #pragma unroll
    for (int m = 0; m < 4; m++) {
        #pragma unroll
        for (int n = 0; n < 4; n++) {
            const int c = wave * 64 + n * 16 + l15;
            #pragma unroll
            for (int rg = 0; rg < 4; rg++) {
                const int r = rowbase + m * 16 + kg * 4 + rg;
                if (r < M) {
                    const size_t off = (size_t)r * HID + c;
                    float v = sspf(acc[m][n][rg]);
                    if (resid) v += resid[off];
                    if (out_f32) ((float*)out)[off] = v;
                    else ((unsigned short*)out)[off] = f2bf(v);
                }
            }
        }
    }
}

__global__ void cvt_w_kernel(const float* __restrict__ src, unsigned short* __restrict__ dst, int n) {
    int i = blockIdx.x * 256 + threadIdx.x;
    if (i < n) dst[i] = f2bf(src[i]);
}

__global__ void zero_f32_kernel(float* __restrict__ p, int n) {
    int i = blockIdx.x * 256 + threadIdx.x;
    if (i < n) p[i] = 0.f;
}

__global__ void be_counts_kernel(const int* __restrict__ src, const int* __restrict__ dst,
                                 const int* __restrict__ batch, int* __restrict__ be,
                                 float* __restrict__ cnt_n, float* __restrict__ cnt_eg) {
    int e = blockIdx.x * 256 + threadIdx.x;
    if (e < NE) {
        int b = batch[src[e]];
        be[e] = b;
        atomicAdd(&cnt_n[dst[e]], 1.f);
        atomicAdd(&cnt_eg[b], 1.f);
    }
}

__global__ void node_counts_kernel(const int* __restrict__ batch, float* __restrict__ cnt_ng) {
    int i = blockIdx.x * 256 + threadIdx.x;
    if (i < NN) atomicAdd(&cnt_ng[batch[i]], 1.f);
}

// one block per edge row (256 threads = 256 cols); e_mid is f32
__global__ void scatter_edges_kernel(const float* __restrict__ emid,
                                     const int* __restrict__ dst, const int* __restrict__ be,
                                     float* __restrict__ e2n_sum, float* __restrict__ e2g_sum) {
    int e = blockIdx.x;
    int c = threadIdx.x;
    float v = emid[(size_t)e * HID + c];
    atomicAdd(&e2n_sum[(size_t)dst[e] * HID + c], v);
    atomicAdd(&e2g_sum[(size_t)be[e] * HID + c], v);
}

// n_mid is bf16
__global__ void scatter_nodes_kernel(const unsigned short* __restrict__ nmid,
                                     const int* __restrict__ batch, float* __restrict__ n2g_sum) {
    int i = blockIdx.x;
    int c = threadIdx.x;
    union { unsigned int u; float f; } x; x.u = ((unsigned int)nmid[(size_t)i * HID + c]) << 16;
    atomicAdd(&n2g_sum[(size_t)batch[i] * HID + c], x.f);
}

__global__ void mean_kernel(const float* __restrict__ sum, const float* __restrict__ cnt,
                            unsigned short* __restrict__ out, int M) {
    int gid = blockIdx.x * 256 + threadIdx.x;
    if (gid < M * HID) {
        int r = gid >> 8;
        out[gid] = f2bf(sum[gid] / fmaxf(cnt[r], 1.f));
    }
}

extern "C" void kernel_launch(void* const* d_in, const int* in_sizes, int n_in,
                              void* d_out, int out_size, void* d_ws, size_t ws_size,
                              hipStream_t stream)
{
    (void)in_sizes; (void)n_in; (void)out_size; (void)ws_size;
    const float* node_feats = (const float*)d_in[0];
    const float* edge_feats = (const float*)d_in[1];
    const float* glob_feats = (const float*)d_in[2];
    const int* edge_index   = (const int*)d_in[3];
    const int* batch        = (const int*)d_in[4];
    const float* Wf[9] = {
        (const float*)d_in[5],  (const float*)d_in[6],  (const float*)d_in[7],
        (const float*)d_in[8],  (const float*)d_in[9],  (const float*)d_in[10],
        (const float*)d_in[11], (const float*)d_in[12], (const float*)d_in[13],
    };
    const int Wn[9] = { HID*HID, HID*HID, HID*HID,
                        HID*4*HID, HID*3*HID, HID*3*HID,
                        HID*HID, HID*HID, HID*HID };

    const int* src = edge_index;        // edge_index[0]
    const int* dst = edge_index + NE;   // edge_index[1]

    float* out_n = (float*)d_out;                       // [NN,256] f32
    float* out_e = out_n + (size_t)NN * HID;            // [NE,256] f32
    float* out_g = out_e + (size_t)NE * HID;            // [NG,256] f32

    // ws layout (~34 MB). Zero-init region first -> single memsetAsync.
    char* ws = (char*)d_ws;
    size_t off = 0;
    auto alloc = [&](size_t bytes) -> char* {
        char* p = ws + off; off += (bytes + 255) & ~(size_t)255; return p;
    };
    float* e2g_sum = (float*)alloc((size_t)NG * HID * 4);
    float* n2g_sum = (float*)alloc((size_t)NG * HID * 4);
    float* cnt_n   = (float*)alloc((size_t)NN * 4);
    float* cnt_eg  = (float*)alloc((size_t)NG * 4);
    float* cnt_ng  = (float*)alloc((size_t)NG * 4);
    size_t zero_bytes = off;
    hipMemsetAsync(d_ws, 0, zero_bytes, stream);

    int* be                  = (int*)alloc((size_t)NE * 4);
    unsigned short* n1       = (unsigned short*)alloc((size_t)NN * HID * 2);
    unsigned short* g1       = (unsigned short*)alloc((size_t)NG * HID * 2);
    unsigned short* e2n_mean = (unsigned short*)alloc((size_t)NN * HID * 2);
    unsigned short* n_mid    = (unsigned short*)alloc((size_t)NN * HID * 2);
    unsigned short* n2g_mean = (unsigned short*)alloc((size_t)NG * HID * 2);
    unsigned short* e2g_mean = (unsigned short*)alloc((size_t)NG * HID * 2);
    unsigned short* g_mid    = (unsigned short*)alloc((size_t)NG * HID * 2);
    unsigned short* Wb[9];
    for (int i = 0; i < 9; i++) Wb[i] = (unsigned short*)alloc((size_t)Wn[i] * 2);

    // Aliases into d_out:
    float* e1      = out_e;   // stage-1 edge activations, f32, in place
    float* e_mid   = out_e;   // edge-MLP output, f32, in place (identity rows)
    float* e2n_sum = out_n;   // f32 atomic target; dead before final node GEMM writes out_n

    // weights -> bf16 (9 tiny launches, 1M elements total)
    for (int i = 0; i < 9; i++)
        cvt_w_kernel<<<(Wn[i] + 255) / 256, 256, 0, stream>>>(Wf[i], Wb[i], Wn[i]);

    zero_f32_kernel<<<(NN * HID + 255) / 256, 256, 0, stream>>>(e2n_sum, NN * HID);
    be_counts_kernel<<<(NE + 255) / 256, 256, 0, stream>>>(src, dst, batch, be, cnt_n, cnt_eg);
    node_counts_kernel<<<(NN + 255) / 256, 256, 0, stream>>>(batch, cnt_ng);

    auto launch_gemm = [&](const ASpec& A, const unsigned short* W, void* o, int of32,
                           const float* resid, int M) {
        gemm_ssp_kernel<<<(M + 63) / 64, 256, 0, stream>>>(A, W, o, of32, resid, M);
    };

    // stage 1: lin_*_1 + ssp
    { ASpec a{}; a.base[0] = node_feats; a.f32mask = 1; a.nblocks = 1;
      launch_gemm(a, Wb[0], n1, 0, nullptr, NN); }
    { ASpec a{}; a.base[0] = edge_feats; a.f32mask = 1; a.nblocks = 1;
      launch_gemm(a, Wb[1], e1, 1, nullptr, NE); }
    { ASpec a{}; a.base[0] = glob_feats; a.f32mask = 1; a.nblocks = 1;
      launch_gemm(a, Wb[2], g1, 0, nullptr, NG); }

    // EdgeModel: gather-concat fused into A-load, K=1024 (in place on out_e)
    { ASpec a{};
      a.base[0] = n1; a.idx[0] = src;
      a.base[1] = n1; a.idx[1] = dst;
      a.base[2] = e1; a.idx[2] = nullptr;
      a.base[3] = g1; a.idx[3] = be;
      a.f32mask = 0b0100;   // block 2 (e1) is f32
      a.nblocks = 4;
      launch_gemm(a, Wb[3], e_mid, 1, nullptr, NE); }

    // scatter-mean edges -> nodes (sum in out_n region) and edges -> graphs
    scatter_edges_kernel<<<NE, 256, 0, stream>>>(e_mid, dst, be, e2n_sum, e2g_sum);
    mean_kernel<<<(NN * HID + 255) / 256, 256, 0, stream>>>(e2n_sum, cnt_n, e2n_mean, NN);

    // NodeModel: K=768 -> n_mid bf16
    { ASpec a{};
      a.base[0] = n1; a.base[1] = e2n_mean;
      a.base[2] = g1; a.idx[2] = batch;
      a.f32mask = 0; a.nblocks = 3;
      launch_gemm(a, Wb[4], n_mid, 0, nullptr, NN); }

    // scatter-mean nodes -> graphs
    scatter_nodes_kernel<<<NN, 256, 0, stream>>>(n_mid, batch, n2g_sum);
    mean_kernel<<<(NG * HID + 255) / 256, 256, 0, stream>>>(n2g_sum, cnt_ng, n2g_mean, NG);
    mean_kernel<<<(NG * HID + 255) / 256, 256, 0, stream>>>(e2g_sum, cnt_eg, e2g_mean, NG);

    // GlobalModel: K=768 -> g_mid bf16
    { ASpec a{};
      a.base[0] = n2g_mean; a.base[1] = e2g_mean; a.base[2] = g1;
      a.f32mask = 0; a.nblocks = 3;
      launch_gemm(a, Wb[5], g_mid, 0, nullptr, NG); }

    // final lin_*_2 + ssp + residual -> f32 d_out (edge runs in place on out_e)
    { ASpec a{}; a.base[0] = n_mid; a.f32mask = 0; a.nblocks = 1;
      launch_gemm(a, Wb[6], out_n, 1, node_feats, NN); }
    { ASpec a{}; a.base[0] = e_mid; a.f32mask = 1; a.nblocks = 1;
      launch_gemm(a, Wb[7], out_e, 1, edge_feats, NE); }
    { ASpec a{}; a.base[0] = g_mid; a.f32mask = 0; a.nblocks = 1;
      launch_gemm(a, Wb[8], out_g, 1, glob_feats, NG); }
}